// Round 6
// baseline (211.731 us; speedup 1.0000x reference)
//
#include <hip/hip_runtime.h>
#include <hip/hip_fp16.h>

#define ODIM 128
#define INV_KEEP 1.1111112f   // float(1.0/0.9)

typedef float f4 __attribute__((ext_vector_type(4)));

// ---------- Fused prep kernel ----------
// Blocks [0, cvt_blocks): convert f32 W -> f16 into workspace (4 elems/thread).
// Blocks [cvt_blocks, ...): build CSR row_ptr from sorted rows[] by scatter.
__global__ void prep_kernel(const float* __restrict__ w, __half* __restrict__ wh,
                            int w_elems,
                            const int* __restrict__ rows, int* __restrict__ row_ptr,
                            int nnz, int n_nodes, int cvt_blocks) {
    if ((int)blockIdx.x < cvt_blocks) {
        int i4 = (blockIdx.x * 256 + threadIdx.x) * 4;
        if (i4 + 3 < w_elems) {
            float4 f = *(const float4*)(w + i4);
            *(__half2*)(wh + i4)     = __floats2half2_rn(f.x, f.y);
            *(__half2*)(wh + i4 + 2) = __floats2half2_rn(f.z, f.w);
        } else {
            for (int k = i4; k < w_elems; ++k) wh[k] = __float2half(w[k]);
        }
    } else {
        int i4 = ((blockIdx.x - cvt_blocks) * 256 + threadIdx.x) * 4;
        if (i4 >= nnz) return;
        int rprev = (i4 == 0) ? -1 : rows[i4 - 1];
        #pragma unroll
        for (int k = 0; k < 4; ++k) {
            int i = i4 + k;
            if (i < nnz) {
                int rc = rows[i];
                for (int r = rprev + 1; r <= rc; ++r) row_ptr[r] = i;
                if (i == nnz - 1)
                    for (int r = rc + 1; r <= n_nodes; ++r) row_ptr[r] = nnz;
                rprev = rc;
            }
        }
    }
}

// ---------- FMA helpers ----------
__device__ __forceinline__ void fma8h(float v, const uint4& h, float (&acc)[8]) {
    const __half2* hh = (const __half2*)&h;
    #pragma unroll
    for (int j = 0; j < 4; ++j) {    // fpext(f16)->fma fuses into v_fma_mix_f32
        acc[2*j]   = fmaf(v, __half2float(__low2half(hh[j])),  acc[2*j]);
        acc[2*j+1] = fmaf(v, __half2float(__high2half(hh[j])), acc[2*j+1]);
    }
}
__device__ __forceinline__ void fma8f(float v, const uint4& a, const uint4& b,
                                      float (&acc)[8]) {
    const float4 fa = *(const float4*)&a;
    const float4 fb = *(const float4*)&b;
    acc[0] = fmaf(v, fa.x, acc[0]);  acc[1] = fmaf(v, fa.y, acc[1]);
    acc[2] = fmaf(v, fa.z, acc[2]);  acc[3] = fmaf(v, fa.w, acc[3]);
    acc[4] = fmaf(v, fb.x, acc[4]);  acc[5] = fmaf(v, fb.y, acc[5]);
    acc[6] = fmaf(v, fb.z, acc[6]);  acc[7] = fmaf(v, fb.w, acc[7]);
}

// ---------- consume one 32-slot region (one row's chunk) ----------
// Predicate-free: staging guarantees v=0 (and c=0) for invalid slots, so all
// 32 slots are consumed unconditionally. Quarter q handles slots q, q+4, ...:
// 8 ds_read_b64 (broadcast within quarter) + 8 gathers in flight, then FMAs.
template <typename WT>
__device__ __forceinline__ void consume32(const char* __restrict__ wbase,
                                          const uint2* __restrict__ reg,
                                          int q, unsigned lo, float (&acc)[8]) {
    uint2 cv[8];
    #pragma unroll
    for (int j = 0; j < 8; ++j) cv[j] = reg[q + 4*j];
    if constexpr (sizeof(WT) == 2) {
        uint4 hA[4], hB[4];
        #pragma unroll
        for (int j = 0; j < 4; ++j)
            hA[j] = *(const uint4*)(wbase + ((cv[j].x << 8) | lo));
        #pragma unroll
        for (int j = 0; j < 4; ++j)
            hB[j] = *(const uint4*)(wbase + ((cv[4+j].x << 8) | lo));
        #pragma unroll
        for (int j = 0; j < 4; ++j) fma8h(__uint_as_float(cv[j].y), hA[j], acc);
        #pragma unroll
        for (int j = 0; j < 4; ++j) fma8h(__uint_as_float(cv[4+j].y), hB[j], acc);
    } else {                         // f32 fallback (workspace too small)
        #pragma unroll
        for (int j = 0; j < 8; ++j) {
            const unsigned o = (cv[j].x << 9) | lo;
            const uint4 a = *(const uint4*)(wbase + o);
            const uint4 b = *(const uint4*)(wbase + o + 16);
            fma8f(__uint_as_float(cv[j].y), a, b, acc);
        }
    }
}

// ---------- Main SpMM: one wave per two rows; per-row private LDS region ----
// Lanes 0-31 stage row0's next 32 nnz into region [0,32); lanes 32-63 stage
// row1's into [32,64). Invalid slots get {c=0, v=0}, so the consume path has
// no predicates at all. Typical rows (<=32 nnz) take exactly one round.
template <typename WT>
__global__ void __launch_bounds__(256, 8)
spmm_kernel(const float* __restrict__ vals,
            const int*   __restrict__ rows,
            const int*   __restrict__ cols,
            const int*   __restrict__ mask,
            const WT*    __restrict__ wmat,
            const float* __restrict__ bias,
            const int*   __restrict__ row_ptr,   // may be null -> binary search
            float*       __restrict__ out,
            int nnz, int n_nodes) {
    __shared__ uint2 cvbuf[4][64];               // [wave][2 regions x 32 slots]
    const int wave = threadIdx.x >> 6;
    const int lane = threadIdx.x & 63;
    const int h    = lane >> 5;                  // half: which row staged
    const int l31  = lane & 31;
    const int q    = lane >> 4;                  // quarter 0..3
    const int s    = lane & 15;                  // sublane within quarter
    const int qh   = q & 1;
    const int r0   = (blockIdx.x * 4 + wave) * 2;
    if (r0 >= n_nodes) return;
    uint2* cvb = cvbuf[wave];

    int o0, o1, o2;                              // row_ptr[r0 .. r0+2]
    if (row_ptr) {
        int li = r0 + (lane < 2 ? (int)lane : 2);
        li = li < n_nodes ? li : n_nodes;
        const int t = row_ptr[li];               // one wave-load, 3 distinct addrs
        o0 = __builtin_amdgcn_readlane(t, 0);
        o1 = __builtin_amdgcn_readlane(t, 1);
        o2 = __builtin_amdgcn_readlane(t, 2);
    } else {
        auto lb_srch = [&](int target) {
            int lo = 0, hi = nnz;
            while (lo < hi) {
                int mid = (lo + hi) >> 1;
                if (rows[mid] < target) lo = mid + 1; else hi = mid;
            }
            return lo;
        };
        o0 = __builtin_amdgcn_readfirstlane(lb_srch(r0));
        o1 = __builtin_amdgcn_readfirstlane(lb_srch(r0 + 1));
        o2 = __builtin_amdgcn_readfirstlane(lb_srch(r0 + 2));
    }

    float a0[8] = {0.f,0.f,0.f,0.f,0.f,0.f,0.f,0.f};
    float a1[8] = {0.f,0.f,0.f,0.f,0.f,0.f,0.f,0.f};
    const char* wbase = (const char*)wmat;
    const unsigned lo16 = (sizeof(WT) == 2) ? ((unsigned)s << 4)
                                            : ((unsigned)s << 5);
    const int base_h = h ? o1 : o0;              // per-lane stage range
    const int end_h  = h ? o2 : o1;
    const int n0 = o1 - o0, n1 = o2 - o1;
    const int nmax = n0 > n1 ? n0 : n1;
    const int rounds = (nmax + 31) >> 5;         // SGPR-uniform
    const int nnzm1 = nnz - 1;

    for (int rd = 0; rd < rounds; ++rd) {
        // ---- stage: 32 slots per row; pads carry {c=0, v=0} ----
        const int idx = base_h + (rd << 5) + l31;
        const int a   = idx < nnzm1 ? idx : nnzm1;
        const int   c = __builtin_nontemporal_load(cols + a);
        const float vv = __builtin_nontemporal_load(vals + a);
        const int   m = __builtin_nontemporal_load(mask + a);
        const bool valid = idx < end_h;
        const unsigned c_st = valid ? (unsigned)c : 0u;
        const float    v_st = (valid && m) ? vv * INV_KEEP : 0.0f;
        cvb[(h << 5) | l31] = make_uint2(c_st, __float_as_uint(v_st));
        // (same-wave ds_write -> ds_read ordered by the LDS pipe; no barrier)

        consume32<WT>(wbase, cvb,      q, lo16, a0);   // row0's region
        consume32<WT>(wbase, cvb + 32, q, lo16, a1);   // row1's region
    }

    // ---- reduce quarter-partials: xor16, fold by qh, xor32 ----
    #pragma unroll
    for (int j = 0; j < 8; ++j) {
        a0[j] += __shfl_xor(a0[j], 16);
        a1[j] += __shfl_xor(a1[j], 16);
    }
    float t0 = qh ? a0[4] : a0[0],  u0 = qh ? a1[4] : a1[0];
    float t1 = qh ? a0[5] : a0[1],  u1 = qh ? a1[5] : a1[1];
    float t2 = qh ? a0[6] : a0[2],  u2 = qh ? a1[6] : a1[2];
    float t3 = qh ? a0[7] : a0[3],  u3 = qh ? a1[7] : a1[3];
    t0 += __shfl_xor(t0, 32);  u0 += __shfl_xor(u0, 32);
    t1 += __shfl_xor(t1, 32);  u1 += __shfl_xor(u1, 32);
    t2 += __shfl_xor(t2, 32);  u2 += __shfl_xor(u2, 32);
    t3 += __shfl_xor(t3, 32);  u3 += __shfl_xor(u3, 32);

    const int cb = 8 * s + 4 * qh;               // this lane's 4-col slot
    const float4 b = ((const float4*)bias)[(unsigned)cb >> 2];
    if (q < 2) {                                 // quarters 0,1 store row r0
        f4 o;
        o.x = t0 + b.x;  o.y = t1 + b.y;  o.z = t2 + b.z;  o.w = t3 + b.w;
        __builtin_nontemporal_store(o, (f4*)(out + (size_t)r0 * ODIM + cb));
    } else if (r0 + 1 < n_nodes) {               // quarters 2,3 store row r0+1
        f4 o;
        o.x = u0 + b.x;  o.y = u1 + b.y;  o.z = u2 + b.z;  o.w = u3 + b.w;
        __builtin_nontemporal_store(o, (f4*)(out + (size_t)(r0 + 1) * ODIM + cb));
    }
}

extern "C" void kernel_launch(void* const* d_in, const int* in_sizes, int n_in,
                              void* d_out, int out_size, void* d_ws, size_t ws_size,
                              hipStream_t stream) {
    const float* vals = (const float*)d_in[0];
    const int*   rows = (const int*)  d_in[1];
    const int*   cols = (const int*)  d_in[2];
    const int*   mask = (const int*)  d_in[3];
    const float* W    = (const float*)d_in[4];
    const float* bias = (const float*)d_in[5];
    float*       out  = (float*)d_out;

    const int nnz     = in_sizes[0];
    const int w_elems = in_sizes[4];             // INPUT_DIM * OUTPUT_DIM
    const int n_nodes = out_size / ODIM;

    // workspace layout: [W as f16 (256B aligned) | row_ptr (n_nodes+1 ints)]
    const size_t wh_bytes = ((size_t)w_elems * sizeof(__half) + 255) & ~(size_t)255;
    const size_t rp_bytes = (size_t)(n_nodes + 1) * sizeof(int);

    __half* wh = nullptr;
    int* row_ptr = nullptr;
    if (ws_size >= wh_bytes + rp_bytes) {
        wh = (__half*)d_ws;
        row_ptr = (int*)((char*)d_ws + wh_bytes);
    } else if (ws_size >= rp_bytes) {
        row_ptr = (int*)d_ws;
    }

    const int cvt_blocks = wh ? (w_elems / 4 + 255) / 256 : 0;
    const int rp_blocks  = row_ptr ? ((nnz + 3) / 4 + 255) / 256 : 0;
    if (cvt_blocks + rp_blocks > 0)
        prep_kernel<<<cvt_blocks + rp_blocks, 256, 0, stream>>>(
            W, wh, w_elems, rows, row_ptr, nnz, n_nodes, cvt_blocks);

    const int blocks = (n_nodes + 7) / 8;   // 8 rows (4 waves x 2 rows) per block
    if (wh) {
        spmm_kernel<__half><<<blocks, 256, 0, stream>>>(
            vals, rows, cols, mask, wh, bias, row_ptr, out, nnz, n_nodes);
    } else {
        spmm_kernel<float><<<blocks, 256, 0, stream>>>(
            vals, rows, cols, mask, W, bias, row_ptr, out, nnz, n_nodes);
    }
}

// Round 7
// 136.055 us; speedup vs baseline: 1.5562x; 1.5562x over previous
//
#include <hip/hip_runtime.h>
#include <hip/hip_fp16.h>

#define ODIM 128
#define INV_KEEP 1.1111112f   // float(1.0/0.9)

typedef float f4 __attribute__((ext_vector_type(4)));

// ---------- Fused prep kernel ----------
// Blocks [0, cvt_blocks): convert f32 W -> f16 into workspace (4 elems/thread).
// Blocks [cvt_blocks, ...): build CSR row_ptr from sorted rows[] by scatter.
__global__ void prep_kernel(const float* __restrict__ w, __half* __restrict__ wh,
                            int w_elems,
                            const int* __restrict__ rows, int* __restrict__ row_ptr,
                            int nnz, int n_nodes, int cvt_blocks) {
    if ((int)blockIdx.x < cvt_blocks) {
        int i4 = (blockIdx.x * 256 + threadIdx.x) * 4;
        if (i4 + 3 < w_elems) {
            float4 f = *(const float4*)(w + i4);
            *(__half2*)(wh + i4)     = __floats2half2_rn(f.x, f.y);
            *(__half2*)(wh + i4 + 2) = __floats2half2_rn(f.z, f.w);
        } else {
            for (int k = i4; k < w_elems; ++k) wh[k] = __float2half(w[k]);
        }
    } else {
        int i4 = ((blockIdx.x - cvt_blocks) * 256 + threadIdx.x) * 4;
        if (i4 >= nnz) return;
        int rprev = (i4 == 0) ? -1 : rows[i4 - 1];
        #pragma unroll
        for (int k = 0; k < 4; ++k) {
            int i = i4 + k;
            if (i < nnz) {
                int rc = rows[i];
                for (int r = rprev + 1; r <= rc; ++r) row_ptr[r] = i;
                if (i == nnz - 1)
                    for (int r = rc + 1; r <= n_nodes; ++r) row_ptr[r] = nnz;
                rprev = rc;
            }
        }
    }
}

// ---------- FMA helpers ----------
__device__ __forceinline__ void fma8h(float v, const uint4& h, float (&acc)[8]) {
    const __half2* hh = (const __half2*)&h;
    #pragma unroll
    for (int j = 0; j < 4; ++j) {    // fpext(f16)->fma fuses into v_fma_mix_f32
        acc[2*j]   = fmaf(v, __half2float(__low2half(hh[j])),  acc[2*j]);
        acc[2*j+1] = fmaf(v, __half2float(__high2half(hh[j])), acc[2*j+1]);
    }
}
__device__ __forceinline__ void fma8f(float v, const uint4& a, const uint4& b,
                                      float (&acc)[8]) {
    const float4 fa = *(const float4*)&a;
    const float4 fb = *(const float4*)&b;
    acc[0] = fmaf(v, fa.x, acc[0]);  acc[1] = fmaf(v, fa.y, acc[1]);
    acc[2] = fmaf(v, fa.z, acc[2]);  acc[3] = fmaf(v, fa.w, acc[3]);
    acc[4] = fmaf(v, fb.x, acc[4]);  acc[5] = fmaf(v, fb.y, acc[5]);
    acc[6] = fmaf(v, fb.z, acc[6]);  acc[7] = fmaf(v, fb.w, acc[7]);
}

// ---------- consume 16 slots of a region (depth-4 gather batch) ----------
// Predicate-free: staging guarantees v=0 (c=0) for invalid slots. Quarter q
// handles slots kb+q, kb+q+4, kb+q+8, kb+q+12: 4 ds_read_b64 (broadcast
// within quarter) + 4 global_load_dwordx4 in flight, then 4x fma8.
// Depth-4 keeps live registers ~48 (r3-proven); depth-8 spilled (r6 lesson).
template <typename WT>
__device__ __forceinline__ void consume16(const char* __restrict__ wbase,
                                          const uint2* __restrict__ reg, int kb,
                                          int q, unsigned lo, float (&acc)[8]) {
    uint2 cv[4];
    #pragma unroll
    for (int j = 0; j < 4; ++j) cv[j] = reg[kb + q + 4*j];
    if constexpr (sizeof(WT) == 2) {
        uint4 h[4];
        #pragma unroll
        for (int j = 0; j < 4; ++j)
            h[j] = *(const uint4*)(wbase + ((cv[j].x << 8) | lo));
        #pragma unroll
        for (int j = 0; j < 4; ++j) fma8h(__uint_as_float(cv[j].y), h[j], acc);
    } else {                         // f32 fallback (workspace too small)
        #pragma unroll
        for (int j = 0; j < 4; ++j) {
            const unsigned o = (cv[j].x << 9) | lo;
            const uint4 a = *(const uint4*)(wbase + o);
            const uint4 b = *(const uint4*)(wbase + o + 16);
            fma8f(__uint_as_float(cv[j].y), a, b, acc);
        }
    }
}

// ---------- Main SpMM: one wave per two rows; per-row private LDS region ----
// Lanes 0-31 stage row0's next 32 nnz into region [0,32); lanes 32-63 stage
// row1's into [32,64). Invalid slots get {c=0, v=0}, so the consume path has
// no predicates at all. Typical rows (<=32 nnz) take exactly one round.
template <typename WT>
__global__ void __launch_bounds__(256, 6)
spmm_kernel(const float* __restrict__ vals,
            const int*   __restrict__ rows,
            const int*   __restrict__ cols,
            const int*   __restrict__ mask,
            const WT*    __restrict__ wmat,
            const float* __restrict__ bias,
            const int*   __restrict__ row_ptr,   // may be null -> binary search
            float*       __restrict__ out,
            int nnz, int n_nodes) {
    __shared__ uint2 cvbuf[4][64];               // [wave][2 regions x 32 slots]
    const int wave = threadIdx.x >> 6;
    const int lane = threadIdx.x & 63;
    const int h    = lane >> 5;                  // half: which row staged
    const int l31  = lane & 31;
    const int q    = lane >> 4;                  // quarter 0..3
    const int s    = lane & 15;                  // sublane within quarter
    const int qh   = q & 1;
    const int r0   = (blockIdx.x * 4 + wave) * 2;
    if (r0 >= n_nodes) return;
    uint2* cvb = cvbuf[wave];

    int o0, o1, o2;                              // row_ptr[r0 .. r0+2]
    if (row_ptr) {
        int li = r0 + (lane < 2 ? (int)lane : 2);
        li = li < n_nodes ? li : n_nodes;
        const int t = row_ptr[li];               // one wave-load, 3 distinct addrs
        o0 = __builtin_amdgcn_readlane(t, 0);
        o1 = __builtin_amdgcn_readlane(t, 1);
        o2 = __builtin_amdgcn_readlane(t, 2);
    } else {
        auto lb_srch = [&](int target) {
            int lo = 0, hi = nnz;
            while (lo < hi) {
                int mid = (lo + hi) >> 1;
                if (rows[mid] < target) lo = mid + 1; else hi = mid;
            }
            return lo;
        };
        o0 = __builtin_amdgcn_readfirstlane(lb_srch(r0));
        o1 = __builtin_amdgcn_readfirstlane(lb_srch(r0 + 1));
        o2 = __builtin_amdgcn_readfirstlane(lb_srch(r0 + 2));
    }

    float a0[8] = {0.f,0.f,0.f,0.f,0.f,0.f,0.f,0.f};
    float a1[8] = {0.f,0.f,0.f,0.f,0.f,0.f,0.f,0.f};
    const char* wbase = (const char*)wmat;
    const unsigned lo16 = (sizeof(WT) == 2) ? ((unsigned)s << 4)
                                            : ((unsigned)s << 5);
    const int base_h = h ? o1 : o0;              // per-lane stage range
    const int end_h  = h ? o2 : o1;
    const int n0 = o1 - o0, n1 = o2 - o1;
    const int nmax = n0 > n1 ? n0 : n1;
    const int rounds = (nmax + 31) >> 5;         // SGPR-uniform
    const int nnzm1 = nnz - 1;

    for (int rd = 0; rd < rounds; ++rd) {
        // ---- stage: 32 slots per row; pads carry {c=0, v=0} ----
        const int idx = base_h + (rd << 5) + l31;
        const int a   = idx < nnzm1 ? idx : nnzm1;
        const int   c = __builtin_nontemporal_load(cols + a);
        const float vv = __builtin_nontemporal_load(vals + a);
        const int   m = __builtin_nontemporal_load(mask + a);
        const bool valid = idx < end_h;
        const unsigned c_st = valid ? (unsigned)c : 0u;
        const float    v_st = (valid && m) ? vv * INV_KEEP : 0.0f;
        cvb[(h << 5) | l31] = make_uint2(c_st, __float_as_uint(v_st));
        // (same-wave ds_write -> ds_read ordered by the LDS pipe; no barrier)

        consume16<WT>(wbase, cvb,  0, q, lo16, a0);   // row0 slots [0,16)
        consume16<WT>(wbase, cvb, 16, q, lo16, a0);   // row0 slots [16,32)
        consume16<WT>(wbase, cvb, 32, q, lo16, a1);   // row1 slots [0,16)
        consume16<WT>(wbase, cvb, 48, q, lo16, a1);   // row1 slots [16,32)
    }

    // ---- reduce quarter-partials: xor16, fold by qh, xor32 ----
    #pragma unroll
    for (int j = 0; j < 8; ++j) {
        a0[j] += __shfl_xor(a0[j], 16);
        a1[j] += __shfl_xor(a1[j], 16);
    }
    float t0 = qh ? a0[4] : a0[0],  u0 = qh ? a1[4] : a1[0];
    float t1 = qh ? a0[5] : a0[1],  u1 = qh ? a1[5] : a1[1];
    float t2 = qh ? a0[6] : a0[2],  u2 = qh ? a1[6] : a1[2];
    float t3 = qh ? a0[7] : a0[3],  u3 = qh ? a1[7] : a1[3];
    t0 += __shfl_xor(t0, 32);  u0 += __shfl_xor(u0, 32);
    t1 += __shfl_xor(t1, 32);  u1 += __shfl_xor(u1, 32);
    t2 += __shfl_xor(t2, 32);  u2 += __shfl_xor(u2, 32);
    t3 += __shfl_xor(t3, 32);  u3 += __shfl_xor(u3, 32);

    const int cb = 8 * s + 4 * qh;               // this lane's 4-col slot
    const float4 b = ((const float4*)bias)[(unsigned)cb >> 2];
    if (q < 2) {                                 // quarters 0,1 store row r0
        f4 o;
        o.x = t0 + b.x;  o.y = t1 + b.y;  o.z = t2 + b.z;  o.w = t3 + b.w;
        __builtin_nontemporal_store(o, (f4*)(out + (size_t)r0 * ODIM + cb));
    } else if (r0 + 1 < n_nodes) {               // quarters 2,3 store row r0+1
        f4 o;
        o.x = u0 + b.x;  o.y = u1 + b.y;  o.z = u2 + b.z;  o.w = u3 + b.w;
        __builtin_nontemporal_store(o, (f4*)(out + (size_t)(r0 + 1) * ODIM + cb));
    }
}

extern "C" void kernel_launch(void* const* d_in, const int* in_sizes, int n_in,
                              void* d_out, int out_size, void* d_ws, size_t ws_size,
                              hipStream_t stream) {
    const float* vals = (const float*)d_in[0];
    const int*   rows = (const int*)  d_in[1];
    const int*   cols = (const int*)  d_in[2];
    const int*   mask = (const int*)  d_in[3];
    const float* W    = (const float*)d_in[4];
    const float* bias = (const float*)d_in[5];
    float*       out  = (float*)d_out;

    const int nnz     = in_sizes[0];
    const int w_elems = in_sizes[4];             // INPUT_DIM * OUTPUT_DIM
    const int n_nodes = out_size / ODIM;

    // workspace layout: [W as f16 (256B aligned) | row_ptr (n_nodes+1 ints)]
    const size_t wh_bytes = ((size_t)w_elems * sizeof(__half) + 255) & ~(size_t)255;
    const size_t rp_bytes = (size_t)(n_nodes + 1) * sizeof(int);

    __half* wh = nullptr;
    int* row_ptr = nullptr;
    if (ws_size >= wh_bytes + rp_bytes) {
        wh = (__half*)d_ws;
        row_ptr = (int*)((char*)d_ws + wh_bytes);
    } else if (ws_size >= rp_bytes) {
        row_ptr = (int*)d_ws;
    }

    const int cvt_blocks = wh ? (w_elems / 4 + 255) / 256 : 0;
    const int rp_blocks  = row_ptr ? ((nnz + 3) / 4 + 255) / 256 : 0;
    if (cvt_blocks + rp_blocks > 0)
        prep_kernel<<<cvt_blocks + rp_blocks, 256, 0, stream>>>(
            W, wh, w_elems, rows, row_ptr, nnz, n_nodes, cvt_blocks);

    const int blocks = (n_nodes + 7) / 8;   // 8 rows (4 waves x 2 rows) per block
    if (wh) {
        spmm_kernel<__half><<<blocks, 256, 0, stream>>>(
            vals, rows, cols, mask, wh, bias, row_ptr, out, nnz, n_nodes);
    } else {
        spmm_kernel<float><<<blocks, 256, 0, stream>>>(
            vals, rows, cols, mask, W, bias, row_ptr, out, nnz, n_nodes);
    }
}

// Round 8
// 134.639 us; speedup vs baseline: 1.5726x; 1.0105x over previous
//
#include <hip/hip_runtime.h>
#include <hip/hip_fp16.h>

#define ODIM 128
#define INV_KEEP 1.1111112f   // float(1.0/0.9)

typedef float f4 __attribute__((ext_vector_type(4)));

// ---------- Fused prep kernel ----------
// Blocks [0, cvt_blocks): convert f32 W -> f16 into workspace (4 elems/thread).
// Blocks [cvt_blocks, ...): build CSR row_ptr from sorted rows[] by scatter.
__global__ void prep_kernel(const float* __restrict__ w, __half* __restrict__ wh,
                            int w_elems,
                            const int* __restrict__ rows, int* __restrict__ row_ptr,
                            int nnz, int n_nodes, int cvt_blocks) {
    if ((int)blockIdx.x < cvt_blocks) {
        int i4 = (blockIdx.x * 256 + threadIdx.x) * 4;
        if (i4 + 3 < w_elems) {
            float4 f = *(const float4*)(w + i4);
            *(__half2*)(wh + i4)     = __floats2half2_rn(f.x, f.y);
            *(__half2*)(wh + i4 + 2) = __floats2half2_rn(f.z, f.w);
        } else {
            for (int k = i4; k < w_elems; ++k) wh[k] = __float2half(w[k]);
        }
    } else {
        int i4 = ((blockIdx.x - cvt_blocks) * 256 + threadIdx.x) * 4;
        if (i4 >= nnz) return;
        int rprev = (i4 == 0) ? -1 : rows[i4 - 1];
        #pragma unroll
        for (int k = 0; k < 4; ++k) {
            int i = i4 + k;
            if (i < nnz) {
                int rc = rows[i];
                for (int r = rprev + 1; r <= rc; ++r) row_ptr[r] = i;
                if (i == nnz - 1)
                    for (int r = rc + 1; r <= n_nodes; ++r) row_ptr[r] = nnz;
                rprev = rc;
            }
        }
    }
}

// ---------- FMA helpers ----------
__device__ __forceinline__ void fma8h(float v, const uint4& h, float (&acc)[8]) {
    const __half2* hh = (const __half2*)&h;
    #pragma unroll
    for (int j = 0; j < 4; ++j) {    // fpext(f16)->fma fuses into v_fma_mix_f32
        acc[2*j]   = fmaf(v, __half2float(__low2half(hh[j])),  acc[2*j]);
        acc[2*j+1] = fmaf(v, __half2float(__high2half(hh[j])), acc[2*j+1]);
    }
}
__device__ __forceinline__ void fma8f(float v, const uint4& a, const uint4& b,
                                      float (&acc)[8]) {
    const float4 fa = *(const float4*)&a;
    const float4 fb = *(const float4*)&b;
    acc[0] = fmaf(v, fa.x, acc[0]);  acc[1] = fmaf(v, fa.y, acc[1]);
    acc[2] = fmaf(v, fa.z, acc[2]);  acc[3] = fmaf(v, fa.w, acc[3]);
    acc[4] = fmaf(v, fb.x, acc[4]);  acc[5] = fmaf(v, fb.y, acc[5]);
    acc[6] = fmaf(v, fb.z, acc[6]);  acc[7] = fmaf(v, fb.w, acc[7]);
}

// One row-segment [kb, ke) of the current 64-nnz chunk: quarter-wave gathers,
// 4 in flight, per-slot predication against the segment end (pad slots clamp
// to ke-1 -> re-fetch a just-used W row, L1-hot; v forced to 0).
template <typename WT>
__device__ __forceinline__ void seg_gather(const char* __restrict__ wbase,
                                           const uint2* __restrict__ cvb,
                                           int kb, int ke, int q, unsigned laneoff,
                                           float (&acc)[8]) {
    for (int k0 = kb; k0 < ke; k0 += 16) {
        const int km  = ke - 1;                    // SGPR
        const int k0q = k0 + q;                    // VGPR (q per-lane)
        const int kc0 = k0q      > km ? km : k0q;
        const int kc1 = k0q + 4  > km ? km : k0q + 4;
        const int kc2 = k0q + 8  > km ? km : k0q + 8;
        const int kc3 = k0q + 12 > km ? km : k0q + 12;
        const uint2 cv0 = cvb[kc0];                // ds_read_b64, bcast/quarter
        const uint2 cv1 = cvb[kc1];
        const uint2 cv2 = cvb[kc2];
        const uint2 cv3 = cvb[kc3];
        const float v0 = (k0q      < ke) ? __uint_as_float(cv0.y) : 0.0f;
        const float v1 = (k0q + 4  < ke) ? __uint_as_float(cv1.y) : 0.0f;
        const float v2 = (k0q + 8  < ke) ? __uint_as_float(cv2.y) : 0.0f;
        const float v3 = (k0q + 12 < ke) ? __uint_as_float(cv3.y) : 0.0f;
        if constexpr (sizeof(WT) == 2) {
            const uint4 h0 = *(const uint4*)(wbase + ((cv0.x << 8) | laneoff));
            const uint4 h1 = *(const uint4*)(wbase + ((cv1.x << 8) | laneoff));
            const uint4 h2 = *(const uint4*)(wbase + ((cv2.x << 8) | laneoff));
            const uint4 h3 = *(const uint4*)(wbase + ((cv3.x << 8) | laneoff));
            fma8h(v0, h0, acc);  fma8h(v1, h1, acc);
            fma8h(v2, h2, acc);  fma8h(v3, h3, acc);
        } else {
            const unsigned o0 = (cv0.x << 9) | laneoff;
            const unsigned o1 = (cv1.x << 9) | laneoff;
            const unsigned o2 = (cv2.x << 9) | laneoff;
            const unsigned o3 = (cv3.x << 9) | laneoff;
            const uint4 a0 = *(const uint4*)(wbase + o0);
            const uint4 b0 = *(const uint4*)(wbase + o0 + 16);
            const uint4 a1 = *(const uint4*)(wbase + o1);
            const uint4 b1 = *(const uint4*)(wbase + o1 + 16);
            const uint4 a2 = *(const uint4*)(wbase + o2);
            const uint4 b2 = *(const uint4*)(wbase + o2 + 16);
            const uint4 a3 = *(const uint4*)(wbase + o3);
            const uint4 b3 = *(const uint4*)(wbase + o3 + 16);
            fma8f(v0, a0, b0, acc);  fma8f(v1, a1, b1, acc);
            fma8f(v2, a2, b2, acc);  fma8f(v3, a3, b3, acc);
        }
    }
}

// ---------- Main SpMM: one wave per TWO consecutive rows ----------
// r3-proven structure (best measured: 49.2 us). Single change vs r3: the
// occupancy bound 6 -> 8 waves/EU. VGPR use is 32, well under the 64 cap at
// 8 waves/EU, so no spill risk (r6's spill was ~85 live regs, a different
// structure). This isolates the occupancy-cap variable against the 49.2 base.
template <typename WT>
__global__ void __launch_bounds__(256, 8)
spmm_kernel(const float* __restrict__ vals,
            const int*   __restrict__ rows,
            const int*   __restrict__ cols,
            const int*   __restrict__ mask,
            const WT*    __restrict__ wmat,
            const float* __restrict__ bias,
            const int*   __restrict__ row_ptr,   // may be null -> binary search
            float*       __restrict__ out,
            int nnz, int n_nodes) {
    __shared__ uint2 cvbuf[256];                 // 64 x {col, val} per wave, 2 KB
    const int wave = threadIdx.x >> 6;
    const int lane = threadIdx.x & 63;
    const int q    = lane >> 4;                  // quarter 0..3
    const int s    = lane & 15;                  // sublane within quarter
    const int r0   = (blockIdx.x * 4 + wave) * 2;
    if (r0 >= n_nodes) return;

    int o0, o1, o2;                              // row_ptr[r0 .. r0+2]
    if (row_ptr) {
        int li = r0 + (lane < 2 ? (int)lane : 2);
        li = li < n_nodes ? li : n_nodes;
        const int t = row_ptr[li];               // one wave-load, 3 distinct addrs
        o0 = __builtin_amdgcn_readlane(t, 0);
        o1 = __builtin_amdgcn_readlane(t, 1);
        o2 = __builtin_amdgcn_readlane(t, 2);
    } else {
        auto lb = [&](int target) {
            int lo = 0, hi = nnz;
            while (lo < hi) {
                int mid = (lo + hi) >> 1;
                if (rows[mid] < target) lo = mid + 1; else hi = mid;
            }
            return lo;
        };
        o0 = __builtin_amdgcn_readfirstlane(lb(r0));
        o1 = __builtin_amdgcn_readfirstlane(lb(r0 + 1));
        o2 = __builtin_amdgcn_readfirstlane(lb(r0 + 2));
    }

    float a0[8] = {0.f,0.f,0.f,0.f,0.f,0.f,0.f,0.f};
    float a1[8] = {0.f,0.f,0.f,0.f,0.f,0.f,0.f,0.f};
    uint2* cvb = &cvbuf[wave << 6];
    const char* wbase = (const char*)wmat;
    const unsigned laneoff = (sizeof(WT) == 2) ? ((unsigned)s << 4)
                                               : ((unsigned)s << 5);
    const int iE = o2;

    for (int base = o0; base < iE; base += 64) {
        const int idx = base + lane;
        const int idc = idx < iE ? idx : (iE - 1);       // clamp (valid: base<iE)
        // one coalesced nontemporal load per stream (read-once)
        const int   c_lane = __builtin_nontemporal_load(cols + idc);
        const float va     = __builtin_nontemporal_load(vals + idc);
        const int   ma     = __builtin_nontemporal_load(mask + idc);
        const float v_st   = (idx < iE && ma) ? va * INV_KEEP : 0.0f;
        cvb[lane] = make_uint2((unsigned)c_lane, __float_as_uint(v_st));
        // (same-wave ds_write -> ds_read ordered by the LDS pipe; no barrier)

        // row0 covers chunk slots [0, ke0), row1 covers [ke0, ke1)  (SGPR math)
        int ke0 = o1 - base;
        ke0 = ke0 < 0 ? 0 : (ke0 > 64 ? 64 : ke0);
        int ke1 = iE - base;
        ke1 = ke1 > 64 ? 64 : ke1;
        seg_gather<WT>(wbase, cvb, 0,   ke0, q, laneoff, a0);
        seg_gather<WT>(wbase, cvb, ke0, ke1, q, laneoff, a1);
    }

    // merge quarter-partials: xor16 (q0+=q1, q2+=q3), fold, xor32.
    #pragma unroll
    for (int j = 0; j < 8; ++j) {
        a0[j] += __shfl_xor(a0[j], 16);
        a1[j] += __shfl_xor(a1[j], 16);
    }
    const int qh = q & 1;
    float t0 = qh ? a0[4] : a0[0],  u0 = qh ? a1[4] : a1[0];
    float t1 = qh ? a0[5] : a0[1],  u1 = qh ? a1[5] : a1[1];
    float t2 = qh ? a0[6] : a0[2],  u2 = qh ? a1[6] : a1[2];
    float t3 = qh ? a0[7] : a0[3],  u3 = qh ? a1[7] : a1[3];
    t0 += __shfl_xor(t0, 32);  u0 += __shfl_xor(u0, 32);
    t1 += __shfl_xor(t1, 32);  u1 += __shfl_xor(u1, 32);
    t2 += __shfl_xor(t2, 32);  u2 += __shfl_xor(u2, 32);
    t3 += __shfl_xor(t3, 32);  u3 += __shfl_xor(u3, 32);

    const int cb = 8 * s + 4 * qh;               // cols for this lane's 16B store
    const float4 b = ((const float4*)bias)[(unsigned)cb >> 2];
    if (q < 2) {                                 // quarters 0,1 store row r0
        f4 o;
        o.x = t0 + b.x;  o.y = t1 + b.y;  o.z = t2 + b.z;  o.w = t3 + b.w;
        __builtin_nontemporal_store(o, (f4*)(out + (size_t)r0 * ODIM + cb));
    } else if (r0 + 1 < n_nodes) {               // quarters 2,3 store row r0+1
        f4 o;
        o.x = u0 + b.x;  o.y = u1 + b.y;  o.z = u2 + b.z;  o.w = u3 + b.w;
        __builtin_nontemporal_store(o, (f4*)(out + (size_t)(r0 + 1) * ODIM + cb));
    }
}

extern "C" void kernel_launch(void* const* d_in, const int* in_sizes, int n_in,
                              void* d_out, int out_size, void* d_ws, size_t ws_size,
                              hipStream_t stream) {
    const float* vals = (const float*)d_in[0];
    const int*   rows = (const int*)  d_in[1];
    const int*   cols = (const int*)  d_in[2];
    const int*   mask = (const int*)  d_in[3];
    const float* W    = (const float*)d_in[4];
    const float* bias = (const float*)d_in[5];
    float*       out  = (float*)d_out;

    const int nnz     = in_sizes[0];
    const int w_elems = in_sizes[4];             // INPUT_DIM * OUTPUT_DIM
    const int n_nodes = out_size / ODIM;

    // workspace layout: [W as f16 (256B aligned) | row_ptr (n_nodes+1 ints)]
    const size_t wh_bytes = ((size_t)w_elems * sizeof(__half) + 255) & ~(size_t)255;
    const size_t rp_bytes = (size_t)(n_nodes + 1) * sizeof(int);

    __half* wh = nullptr;
    int* row_ptr = nullptr;
    if (ws_size >= wh_bytes + rp_bytes) {
        wh = (__half*)d_ws;
        row_ptr = (int*)((char*)d_ws + wh_bytes);
    } else if (ws_size >= rp_bytes) {
        row_ptr = (int*)d_ws;
    }

    const int cvt_blocks = wh ? (w_elems / 4 + 255) / 256 : 0;
    const int rp_blocks  = row_ptr ? ((nnz + 3) / 4 + 255) / 256 : 0;
    if (cvt_blocks + rp_blocks > 0)
        prep_kernel<<<cvt_blocks + rp_blocks, 256, 0, stream>>>(
            W, wh, w_elems, rows, row_ptr, nnz, n_nodes, cvt_blocks);

    const int blocks = (n_nodes + 7) / 8;   // 8 rows (4 waves x 2 rows) per block
    if (wh) {
        spmm_kernel<__half><<<blocks, 256, 0, stream>>>(
            vals, rows, cols, mask, wh, bias, row_ptr, out, nnz, n_nodes);
    } else {
        spmm_kernel<float><<<blocks, 256, 0, stream>>>(
            vals, rows, cols, mask, W, bias, row_ptr, out, nnz, n_nodes);
    }
}